// Round 10
// baseline (411.872 us; speedup 1.0000x reference)
//
#include <hip/hip_runtime.h>

typedef float     v2f __attribute__((ext_vector_type(2)));
typedef _Float16  v2h __attribute__((ext_vector_type(2)));
typedef unsigned int uint;

#define BB 2048
#define TT 1024
#define CC 9
#define HH 36
#define G3 108                    // 3*HH gate rows
#define CSTEPS 64                 // timesteps per x-chunk
#define CF (CSTEPS * CC)          // 576 f32 per chunk
#define XP 12                     // padded f32 per step in xpad (48 B)
#define NCH (TT / CSTEPS)         // 16 chunks

// Compiler-level ordering fence for same-wave LDS write->read handoffs.
// (R7/R8 bug: differently-typed pointer puns into the same __shared__ array
// let TBAA claim no-alias and the scheduler hoisted combine reads above the
// same-step scatter write -> one-step-stale recurrence, deterministic 0.258.)
__device__ __forceinline__ void lds_fence() {
    asm volatile("" ::: "memory");            // IR-level: nothing crosses
    __builtin_amdgcn_sched_barrier(0);        // MIR-level: nothing crosses
}

__device__ __forceinline__ void pinh(v2h& v) {
    uint t = __builtin_bit_cast(uint, v);
    asm volatile("" : "+v"(t));
    v = __builtin_bit_cast(v2h, t);
}
__device__ __forceinline__ void pin2f(v2f& v) {
    uint64_t t = __builtin_bit_cast(uint64_t, v);
    asm volatile("" : "+v"(t));
    v = __builtin_bit_cast(v2f, t);
}

// async global->LDS, 4 B per lane (wave writes 256 B: lds_base + lane*4)
__device__ __forceinline__ void gload4(const float* g, float* l) {
    __builtin_amdgcn_global_load_lds(
        (const __attribute__((address_space(1))) unsigned int*)g,
        (__attribute__((address_space(3))) unsigned int*)l,
        4, 0, 0);
}

// One wave per batch element. Lane l < 54 owns gate-rows (2l, 2l+1) of 108
// (r:0..35, z:36..71, n:72..107). h-path fp16 (fdot2, f32 accum, RTE) -- R6's
// proven numerics; x-path f32. Each lane writes (ax0,ah0,ax1,ah1) b128 to
// pbuf so row i's parts sit at pbuf[2i],pbuf[2i+1]; lanes < 36 combine +
// activate + broadcast h. Explicit lds_fence() at every same-wave LDS
// write->read handoff (no barriers in a 1-wave block; HW DS ordering is
// per-wave, but the COMPILER must be fenced).
__global__ __launch_bounds__(64)
__attribute__((amdgpu_waves_per_eu(2, 2)))
void gru_kernel(
    const float* __restrict__ x,      // (B,T,C)
    const float* __restrict__ w_ih,   // (3H,C)
    const float* __restrict__ w_hh,   // (3H,H)
    const float* __restrict__ b_ih,   // (3H)
    const float* __restrict__ b_hh,   // (3H)
    const float* __restrict__ w_head, // (1,H)
    const float* __restrict__ b_head, // (1)
    float* __restrict__ out)          // (B,1)
{
    const int b = blockIdx.x;
    const int l = threadIdx.x;

    __shared__ __align__(16) float    fstage[CF];          // gload_lds dest (linear)
    __shared__ __align__(16) float    xpad[CSTEPS * XP];   // padded f32 x per step
    __shared__ __align__(16) float    pbuf[256];           // 2 preact parts per row (+pad)
    __shared__ __align__(16) _Float16 hbuf[40];            // h broadcast (36 + pad)

    // rows owned by this lane (lanes >= 54 clamp to row 107; their pbuf
    // writes land at pbuf[216..255] = pad, never read)
    const int i0 = (2 * l     < G3) ? 2 * l     : G3 - 1;
    const int i1 = (2 * l + 1 < G3) ? 2 * l + 1 : G3 - 1;

    // ---- per-lane weights: w_hh fp16 (RTE), w_ih f32 ----
    v2h wh0[18], wh1[18];
    v2f wx0[4], wx1[4];
    float w80, w81;
    float bA0, bB0, bA1, bB1;     // per-row bias split: x-part init / h-part init
    {
        const float* p0 = w_hh + (size_t)i0 * HH;
        const float* p1 = w_hh + (size_t)i1 * HH;
#pragma unroll
        for (int k = 0; k < 18; ++k) {
            wh0[k] = (v2h){(_Float16)p0[2*k], (_Float16)p0[2*k+1]};
            wh1[k] = (v2h){(_Float16)p1[2*k], (_Float16)p1[2*k+1]};
        }
        const float* q0 = w_ih + (size_t)i0 * CC;
        const float* q1 = w_ih + (size_t)i1 * CC;
#pragma unroll
        for (int p = 0; p < 4; ++p) {
            wx0[p] = (v2f){q0[2*p], q0[2*p+1]};
            wx1[p] = (v2f){q1[2*p], q1[2*p+1]};
        }
        w80 = q0[8];
        w81 = q1[8];
        const bool n0 = i0 >= 2 * HH, n1 = i1 >= 2 * HH;
        bA0 = n0 ? b_ih[i0] : (b_ih[i0] + b_hh[i0]);
        bB0 = n0 ? b_hh[i0] : 0.f;
        bA1 = n1 ? b_ih[i1] : (b_ih[i1] + b_hh[i1]);
        bB1 = n1 ? b_hh[i1] : 0.f;
    }
    // ---- pin: loads may not be sunk/rematerialized into the loop ----
#pragma unroll
    for (int k = 0; k < 18; ++k) { pinh(wh0[k]); pinh(wh1[k]); }
#pragma unroll
    for (int p = 0; p < 4; ++p) { pin2f(wx0[p]); pin2f(wx1[p]); }
    asm volatile("" : "+v"(w80), "+v"(w81));
    asm volatile("" : "+v"(bA0), "+v"(bB0), "+v"(bA1), "+v"(bB1));

    const float* xg = x + (size_t)b * (TT * CC);

    // prefetch chunk 0 (f32, linear)
#pragma unroll
    for (int k = 0; k < 9; ++k) gload4(xg + k * 64 + l, &fstage[k * 64]);

    v2h h2[18];
#pragma unroll
    for (int k = 0; k < 18; ++k) h2[k] = (v2h){(_Float16)0.f, (_Float16)0.f};
    float h_own = 0.f;

    for (int c = 0; c < NCH; ++c) {
        asm volatile("s_waitcnt vmcnt(0)" ::: "memory");
        __builtin_amdgcn_sched_barrier(0);

        // ---- restage chunk to padded layout: lane l handles timestep l ----
        {
            float xf[9];
#pragma unroll
            for (int q = 0; q < 9; ++q) xf[q] = fstage[l * 9 + q];
            *(float4*)&xpad[l * XP]     = (float4){xf[0], xf[1], xf[2], xf[3]};
            *(float4*)&xpad[l * XP + 4] = (float4){xf[4], xf[5], xf[6], xf[7]};
            xpad[l * XP + 8] = xf[8];
        }
        lds_fence();   // xpad writes -> step reads (cross-lane, same wave)

        // ---- issue next chunk's gloads (in flight across the 64 steps) ----
        if (c + 1 < NCH) {
            const float* src = xg + (size_t)(c + 1) * CF;
#pragma unroll
            for (int k = 0; k < 9; ++k) gload4(src + k * 64 + l, &fstage[k * 64]);
        }

#pragma unroll 2
        for (int s = 0; s < CSTEPS; ++s) {
            // x_t: 9 f32, uniform-address vector reads
            float4 xa = *(const float4*)&xpad[s * XP];
            float4 xb = *(const float4*)&xpad[s * XP + 4];
            float  x8 = xpad[s * XP + 8];
            v2f X0 = (v2f){xa.x, xa.y};
            v2f X1 = (v2f){xa.z, xa.w};
            v2f X2 = (v2f){xb.x, xb.y};
            v2f X3 = (v2f){xb.z, xb.w};

            // x-parts (f32 pk_fma chains)
            v2f a0 = (v2f){bA0, 0.f};
            v2f a1 = (v2f){bA1, 0.f};
            a0 = __builtin_elementwise_fma(wx0[0], X0, a0);
            a1 = __builtin_elementwise_fma(wx1[0], X0, a1);
            a0 = __builtin_elementwise_fma(wx0[1], X1, a0);
            a1 = __builtin_elementwise_fma(wx1[1], X1, a1);
            a0 = __builtin_elementwise_fma(wx0[2], X2, a0);
            a1 = __builtin_elementwise_fma(wx1[2], X2, a1);
            a0 = __builtin_elementwise_fma(wx0[3], X3, a0);
            a1 = __builtin_elementwise_fma(wx1[3], X3, a1);
            float ax0 = fmaf(w80, x8, a0.x + a0.y);
            float ax1 = fmaf(w81, x8, a1.x + a1.y);

            // h-parts (fp16 dot2, f32 accum)
            float ah0 = bB0, ah1 = bB1;
#pragma unroll
            for (int k = 0; k < 18; ++k) {
                ah0 = __builtin_amdgcn_fdot2(wh0[k], h2[k], ah0, false);
                ah1 = __builtin_amdgcn_fdot2(wh1[k], h2[k], ah1, false);
            }

            // row i parts land at pbuf[2i], pbuf[2i+1]
            *(float4*)&pbuf[4 * l] = (float4){ax0, ah0, ax1, ah1};
            lds_fence();   // pbuf scatter -> combine reads (THE R7/R8 bug)

            if (l < HH) {
                v2f rp = *(const v2f*)&pbuf[2 * l];
                v2f zp = *(const v2f*)&pbuf[2 * (HH + l)];
                v2f np = *(const v2f*)&pbuf[2 * (2 * HH + l)];
                float sr = rp.x + rp.y;
                float sz = zp.x + zp.y;
                float r = __builtin_amdgcn_rcpf(1.f + __expf(-sr));
                float z = __builtin_amdgcn_rcpf(1.f + __expf(-sz));
                float a = np.x + r * np.y;
                float n = 1.f - 2.f * __builtin_amdgcn_rcpf(__expf(2.f * a) + 1.f);
                h_own = z * (h_own - n) + n;
                hbuf[l] = (_Float16)h_own;   // RTE
            }
            lds_fence();   // hbuf write -> h2 reads

            // h_t back to every lane as fp16 pairs (uniform reads; 1-wave
            // block: per-wave DS ordering, compiler fenced above)
#pragma unroll
            for (int q = 0; q < 4; ++q) {
                uint4 t4 = ((const uint4*)hbuf)[q];
                h2[4*q+0] = __builtin_bit_cast(v2h, t4.x);
                h2[4*q+1] = __builtin_bit_cast(v2h, t4.y);
                h2[4*q+2] = __builtin_bit_cast(v2h, t4.z);
                h2[4*q+3] = __builtin_bit_cast(v2h, t4.w);
            }
            {
                uint2 t2 = ((const uint2*)hbuf)[8];
                h2[16] = __builtin_bit_cast(v2h, t2.x);
                h2[17] = __builtin_bit_cast(v2h, t2.y);
            }
        }
    }

    // head: out[b] = sum_j h[j] * w_head[j] + b_head
    float whead = (l < HH) ? w_head[l] : 0.f;
    float v = (l < HH) ? h_own * whead : 0.f;
#pragma unroll
    for (int off = 32; off; off >>= 1) v += __shfl_down(v, off);
    if (l == 0) out[b] = v + b_head[0];
}

extern "C" void kernel_launch(void* const* d_in, const int* in_sizes, int n_in,
                              void* d_out, int out_size, void* d_ws, size_t ws_size,
                              hipStream_t stream) {
    const float* x      = (const float*)d_in[0];
    const float* w_ih   = (const float*)d_in[1];
    const float* w_hh   = (const float*)d_in[2];
    const float* b_ih   = (const float*)d_in[3];
    const float* b_hh   = (const float*)d_in[4];
    const float* w_head = (const float*)d_in[5];
    const float* b_head = (const float*)d_in[6];
    float* out = (float*)d_out;

    gru_kernel<<<BB, 64, 0, stream>>>(x, w_ih, w_hh, b_ih, b_hh,
                                      w_head, b_head, out);
}